// Round 11
// baseline (85.848 us; speedup 1.0000x reference)
//
#include <hip/hip_runtime.h>

#define NPB 256  // points per block

typedef float floatx4 __attribute__((ext_vector_type(4)));

__global__ __launch_bounds__(256) void g2_invariant_kernel(
        const float* __restrict__ x,
        const float* __restrict__ y,
        const float* __restrict__ z,
        float* __restrict__ out,
        int npts) {
    // Aliased LDS: inputs (3 * NPB*7 floats = 21504 B) staged first, consumed
    // into registers, then the SAME memory holds outputs (NPB*10 floats).
    // 21504 B -> 7 blocks/CU.
    //
    // Final config (2x2 NT matrix corner): ALL input loads nontemporal and
    // ALL output stores nontemporal. Mechanism (established R7-R10): `nt`
    // loads stream ~45% faster from HBM (cold-pass 143 -> 98.7 us; evict-
    // first, no allocate pressure), independent of any L3-residency effect
    // (FETCH_SIZE frozen at 172 GB across all configs; f=0.36 == f=0.5).
    // NT stores independently worth -3.7 us (full-line coalesced from LDS
    // staging -> no RMW amplification, WRITE_SIZE exactly 163840 KB).
    __shared__ float smem[NPB * 7 * 3];
    float* const sx = smem;
    float* const sy = smem + NPB * 7;
    float* const sz = smem + NPB * 7 * 2;
    float* const so = smem;  // alias — valid after barrier #2

    const int t = threadIdx.x;
    const size_t p0 = (size_t)blockIdx.x * NPB;
    const int cnt = (int)min((long long)NPB, (long long)npts - (long long)p0);

    // ---- global -> LDS staging (all nontemporal) ----
    if (cnt == NPB) {
        const floatx4* gx = (const floatx4*)(x + p0 * 7);
        const floatx4* gy = (const floatx4*)(y + p0 * 7);
        const floatx4* gz = (const floatx4*)(z + p0 * 7);
        floatx4* lx = (floatx4*)sx;
        floatx4* ly = (floatx4*)sy;
        floatx4* lz = (floatx4*)sz;
        // NPB*7/4 = 448 float4 per array per block
#pragma unroll
        for (int i = t; i < NPB * 7 / 4; i += 256) {
            lx[i] = __builtin_nontemporal_load(gx + i);
            ly[i] = __builtin_nontemporal_load(gy + i);
            lz[i] = __builtin_nontemporal_load(gz + i);
        }
    } else if (cnt > 0) {
        for (int i = t; i < cnt * 7; i += 256) {
            sx[i] = x[p0 * 7 + i];
            sy[i] = y[p0 * 7 + i];
            sz[i] = z[p0 * 7 + i];
        }
    }
    __syncthreads();  // barrier 1: staging complete

    // ---- LDS -> registers ----
    float X[7], Y[7], Z[7];
    if (t < cnt) {
#pragma unroll
        for (int c = 0; c < 7; ++c) {
            X[c] = sx[t * 7 + c];
            Y[c] = sy[t * 7 + c];
            Z[c] = sz[t * 7 + c];
        }
    }
    __syncthreads();  // barrier 2: all reads done; LDS reusable for output

    // ---- per-point compute, write to aliased output staging ----
    if (t < cnt) {
        float sxx = 0.f, sxy = 0.f, syy = 0.f, sxz = 0.f, syz = 0.f, szz = 0.f;
#pragma unroll
        for (int c = 0; c < 7; ++c) {
            sxx = fmaf(X[c], X[c], sxx);
            sxy = fmaf(X[c], Y[c], sxy);
            syy = fmaf(Y[c], Y[c], syy);
            sxz = fmaf(X[c], Z[c], sxz);
            syz = fmaf(Y[c], Z[c], syz);
            szz = fmaf(Z[c], Z[c], szz);
        }
#define W(a, b) (X[a] * Y[b] - X[b] * Y[a])
        // G2 cross product (Bryant convention), c_k = phi_ijk x_i y_j
        const float c0 = W(1, 2) + W(3, 4) + W(5, 6);
        const float c1 = W(2, 0) + W(3, 5) - W(4, 6);
        const float c2 = W(0, 1) - W(3, 6) - W(4, 5);
        const float c3 = W(4, 0) + W(5, 1) - W(6, 2);
        const float c4 = W(0, 3) + W(1, 6) + W(2, 5);
        const float c5 = W(6, 0) + W(1, 3) - W(2, 4);
        const float c6 = W(0, 5) - W(1, 4) - W(2, 3);
#undef W
        const float scc = c0 * c0 + c1 * c1 + c2 * c2 + c3 * c3 +
                          c4 * c4 + c5 * c5 + c6 * c6;
        const float tr = c0 * Z[0] + c1 * Z[1] + c2 * Z[2] + c3 * Z[3] +
                         c4 * Z[4] + c5 * Z[5] + c6 * Z[6];

        float* o = &so[t * 10];
        o[0] = sqrtf(sxx);   // ||x||
        o[1] = sxy;          // <x,y>
        o[2] = sqrtf(syy);   // ||y||
        o[3] = sqrtf(scc);   // ||x cross y||
        o[4] = sxz;          // <x,z>
        o[5] = syz;          // <y,z>
        o[6] = sqrtf(szz);   // ||z||
        o[7] = tr;           // phi(x,y,z) = <x cross y, z>
        o[8] = 0.f;          // phi(x,x,y) == 0 by antisymmetry
        o[9] = 0.f;          // phi(y,y,z) == 0 by antisymmetry
    }
    __syncthreads();  // barrier 3: output staging complete

    // ---- LDS -> global output (nontemporal, full-line coalesced) ----
    if (cnt == NPB) {
        floatx4* go = (floatx4*)(out + p0 * 10);
        const floatx4* lo = (const floatx4*)so;
        // NPB*10/4 = 640 float4 per block; each wave instr covers 1 KB
        __builtin_nontemporal_store(lo[t], go + t);
        __builtin_nontemporal_store(lo[t + 256], go + t + 256);
        if (t < 128) __builtin_nontemporal_store(lo[t + 512], go + t + 512);
    } else if (cnt > 0) {
        for (int i = t; i < cnt * 10; i += 256) out[p0 * 10 + i] = so[i];
    }
}

extern "C" void kernel_launch(void* const* d_in, const int* in_sizes, int n_in,
                              void* d_out, int out_size, void* d_ws, size_t ws_size,
                              hipStream_t stream) {
    const float* x = (const float*)d_in[0];
    const float* y = (const float*)d_in[1];
    const float* z = (const float*)d_in[2];
    float* out = (float*)d_out;
    const int npts = in_sizes[0] / 7;  // 256*16384 = 4194304
    const int nblocks = (npts + NPB - 1) / NPB;
    g2_invariant_kernel<<<nblocks, 256, 0, stream>>>(x, y, z, out, npts);
}

// Round 12
// 79.923 us; speedup vs baseline: 1.0741x; 1.0741x over previous
//
#include <hip/hip_runtime.h>

#define NPB 256  // points per block

typedef float floatx4 __attribute__((ext_vector_type(4)));

__global__ __launch_bounds__(256) void g2_invariant_kernel(
        const float* __restrict__ x,
        const float* __restrict__ y,
        const float* __restrict__ z,
        float* __restrict__ out,
        int npts, int nt_cutoff) {
    // Aliased LDS: inputs (3 * NPB*7 floats = 21504 B) staged first, consumed
    // into registers, then the SAME memory holds outputs (NPB*10 floats).
    // 21504 B -> 7 blocks/CU.
    //
    // BEST-MEASURED CONFIG (restored R9; full NT 2x2 matrix mapped R7-R11):
    //   - blocks < nt_cutoff (f=0.5) load inputs NONTEMPORAL: partial
    //     evict-first marking protects the temporal remainder's L3
    //     residency. Interior optimum: f=0 -> 94.8us, f=0.36 -> 80.6,
    //     f=0.5 -> 80.2, f=1.0 -> 85.8 (all-NT forfeits L3 hits entirely,
    //     landing at the pure-HBM roofline 520MB/6.3TBps = 82.7us).
    //   - Output stores NONTEMPORAL from LDS staging (full-line coalesced,
    //     no RMW amplification; -3.7us isolated at f=0).
    // Achieves 80.2us = 6.48 TB/s logical, ABOVE the 6.29 TB/s D2D copy
    // ceiling (L3 hits). Three structural alternatives (reg-pipeline,
    // global_load_lds DMA pipeline) all landed 98-108us; this simple
    // 2-barrier structure + tuned NT hints is the measured optimum.
    __shared__ float smem[NPB * 7 * 3];
    float* const sx = smem;
    float* const sy = smem + NPB * 7;
    float* const sz = smem + NPB * 7 * 2;
    float* const so = smem;  // alias — valid after barrier #2

    const int t = threadIdx.x;
    const size_t p0 = (size_t)blockIdx.x * NPB;
    const int cnt = (int)min((long long)NPB, (long long)npts - (long long)p0);

    // ---- global -> LDS staging (vectorized fast path) ----
    if (cnt == NPB) {
        const floatx4* gx = (const floatx4*)(x + p0 * 7);
        const floatx4* gy = (const floatx4*)(y + p0 * 7);
        const floatx4* gz = (const floatx4*)(z + p0 * 7);
        floatx4* lx = (floatx4*)sx;
        floatx4* ly = (floatx4*)sy;
        floatx4* lz = (floatx4*)sz;
        // NPB*7/4 = 448 float4 per array per block
        if (blockIdx.x < (unsigned)nt_cutoff) {
#pragma unroll
            for (int i = t; i < NPB * 7 / 4; i += 256) {
                lx[i] = __builtin_nontemporal_load(gx + i);
                ly[i] = __builtin_nontemporal_load(gy + i);
                lz[i] = __builtin_nontemporal_load(gz + i);
            }
        } else {
#pragma unroll
            for (int i = t; i < NPB * 7 / 4; i += 256) {
                lx[i] = gx[i];
                ly[i] = gy[i];
                lz[i] = gz[i];
            }
        }
    } else if (cnt > 0) {
        for (int i = t; i < cnt * 7; i += 256) {
            sx[i] = x[p0 * 7 + i];
            sy[i] = y[p0 * 7 + i];
            sz[i] = z[p0 * 7 + i];
        }
    }
    __syncthreads();  // barrier 1: staging complete

    // ---- LDS -> registers ----
    float X[7], Y[7], Z[7];
    if (t < cnt) {
#pragma unroll
        for (int c = 0; c < 7; ++c) {
            X[c] = sx[t * 7 + c];
            Y[c] = sy[t * 7 + c];
            Z[c] = sz[t * 7 + c];
        }
    }
    __syncthreads();  // barrier 2: all reads done; LDS reusable for output

    // ---- per-point compute, write to aliased output staging ----
    if (t < cnt) {
        float sxx = 0.f, sxy = 0.f, syy = 0.f, sxz = 0.f, syz = 0.f, szz = 0.f;
#pragma unroll
        for (int c = 0; c < 7; ++c) {
            sxx = fmaf(X[c], X[c], sxx);
            sxy = fmaf(X[c], Y[c], sxy);
            syy = fmaf(Y[c], Y[c], syy);
            sxz = fmaf(X[c], Z[c], sxz);
            syz = fmaf(Y[c], Z[c], syz);
            szz = fmaf(Z[c], Z[c], szz);
        }
#define W(a, b) (X[a] * Y[b] - X[b] * Y[a])
        // G2 cross product (Bryant convention), c_k = phi_ijk x_i y_j
        const float c0 = W(1, 2) + W(3, 4) + W(5, 6);
        const float c1 = W(2, 0) + W(3, 5) - W(4, 6);
        const float c2 = W(0, 1) - W(3, 6) - W(4, 5);
        const float c3 = W(4, 0) + W(5, 1) - W(6, 2);
        const float c4 = W(0, 3) + W(1, 6) + W(2, 5);
        const float c5 = W(6, 0) + W(1, 3) - W(2, 4);
        const float c6 = W(0, 5) - W(1, 4) - W(2, 3);
#undef W
        const float scc = c0 * c0 + c1 * c1 + c2 * c2 + c3 * c3 +
                          c4 * c4 + c5 * c5 + c6 * c6;
        const float tr = c0 * Z[0] + c1 * Z[1] + c2 * Z[2] + c3 * Z[3] +
                         c4 * Z[4] + c5 * Z[5] + c6 * Z[6];

        float* o = &so[t * 10];
        o[0] = sqrtf(sxx);   // ||x||
        o[1] = sxy;          // <x,y>
        o[2] = sqrtf(syy);   // ||y||
        o[3] = sqrtf(scc);   // ||x cross y||
        o[4] = sxz;          // <x,z>
        o[5] = syz;          // <y,z>
        o[6] = sqrtf(szz);   // ||z||
        o[7] = tr;           // phi(x,y,z) = <x cross y, z>
        o[8] = 0.f;          // phi(x,x,y) == 0 by antisymmetry
        o[9] = 0.f;          // phi(y,y,z) == 0 by antisymmetry
    }
    __syncthreads();  // barrier 3: output staging complete

    // ---- LDS -> global output (nontemporal, full-line coalesced) ----
    if (cnt == NPB) {
        floatx4* go = (floatx4*)(out + p0 * 10);
        const floatx4* lo = (const floatx4*)so;
        // NPB*10/4 = 640 float4 per block; each wave instr covers 1 KB
        __builtin_nontemporal_store(lo[t], go + t);
        __builtin_nontemporal_store(lo[t + 256], go + t + 256);
        if (t < 128) __builtin_nontemporal_store(lo[t + 512], go + t + 512);
    } else if (cnt > 0) {
        for (int i = t; i < cnt * 10; i += 256) out[p0 * 10 + i] = so[i];
    }
}

extern "C" void kernel_launch(void* const* d_in, const int* in_sizes, int n_in,
                              void* d_out, int out_size, void* d_ws, size_t ws_size,
                              hipStream_t stream) {
    const float* x = (const float*)d_in[0];
    const float* y = (const float*)d_in[1];
    const float* z = (const float*)d_in[2];
    float* out = (float*)d_out;
    const int npts = in_sizes[0] / 7;  // 256*16384 = 4194304
    const int nblocks = (npts + NPB - 1) / NPB;
    // NT fraction f = 0.50 (measured optimum of the f-sweep).
    const int nt_cutoff = (int)((long long)nblocks * 50 / 100);
    g2_invariant_kernel<<<nblocks, 256, 0, stream>>>(x, y, z, out, npts,
                                                     nt_cutoff);
}